// Round 8
// baseline (169.834 us; speedup 1.0000x reference)
//
#include <hip/hip_runtime.h>

// ---------------------------------------------------------------------------
// out[b,i] = (x@L^T)[b,i] + quad_mean[b] + cubic_mean[b] + (i==0)*cT[b] + (i==1)*cH[b]
// quad_mean[b] = sum_h relu(x@qW1 + qb1)[b,h] * colmean(qW2)[h] + mean(qb2)
//
// Round 15: port nl_gemm to the 8-phase 256^2 counted-vmcnt schedule (the
// m201-verified structure; r4 counters proved the 2-barrier loop is
// latency-bound at MfmaUtil 18%). Design (self-derived, paper-verified):
//  - 512 thr = 8 waves (2M x 4N), per-wave out 128x64, acc[8][4] f32x4.
//  - LDS 128KB: per operand a 4-slot ring of K-HALF tiles (256 rows x 32 k).
//    Half s=2t+h: consumed phases 2s,2s+1; staged at 2s-6 (A) / 2s-5 (B).
//    Slot reuse: previous occupant's last read = stage-phase-1 (barriered).
//  - Phase: 8 ds_read -> stage 1 half (2 gload_lds/thr) -> vmcnt(8)
//    [tail 6/4/2/0] -> s_barrier -> setprio(1) -> 16 MFMA -> setprio(0)
//    -> s_barrier. vmcnt-before-barrier publishes arrival to ALL waves.
//  - Swizzle for 64B-row halves: slot = kc2 ^ ((row>>1)&3) -> 2-way max
//    (free); staged via pre-swizzled per-lane global src, linear LDS dst.
//  - Prologue 6 halves + vmcnt(4); K=512 -> 32 phases fully unrolled.
// lin_gemm + prep_conv bit-identical to r7 (169.5us best).
// ---------------------------------------------------------------------------

#define OMEGA_F 0.5235987755982988f

typedef __attribute__((ext_vector_type(8))) short short8;
typedef __attribute__((ext_vector_type(4))) float f32x4;

__device__ __forceinline__ unsigned short f2bf(float f) {
  union { float f; unsigned int u; } a;
  a.f = f;
  unsigned int u = a.u;
  return (unsigned short)((u + 0x7fffu + ((u >> 16) & 1u)) >> 16);
}

// async global -> LDS, 16 B per lane; LDS dst wave-uniform, lane i -> base+i*16
__device__ __forceinline__ void gload16(const void* g, void* l) {
  __builtin_amdgcn_global_load_lds(
      (const __attribute__((address_space(1))) unsigned int*)g,
      (__attribute__((address_space(3))) unsigned int*)l, 16, 0, 0);
}

// ---- k1: all prep work in one launch (unchanged, verified) -----------------
__global__ void prep_conv(const float* __restrict__ fc, const float* __restrict__ qW1,
                          const float* __restrict__ cW1, const float* __restrict__ t,
                          const float* __restrict__ qW2, const float* __restrict__ cW2,
                          const float* __restrict__ qb2, const float* __restrict__ cb2,
                          const float4* __restrict__ x4, const float* __restrict__ x,
                          const float* __restrict__ tW1, const float* __restrict__ tb1,
                          const float* __restrict__ tW2, const float* __restrict__ tb2,
                          const float* __restrict__ hW1, const float* __restrict__ hb1,
                          const float* __restrict__ hW2, const float* __restrict__ hb2,
                          unsigned short* __restrict__ WT, uint2* __restrict__ xb,
                          float* __restrict__ qw2m, float* __restrict__ cw2m,
                          float* __restrict__ b2m, float* __restrict__ cT,
                          float* __restrict__ cH, float* __restrict__ rowadd) {
  int b = blockIdx.x, tdx = threadIdx.x;
  if (b < 3072) {
    // WcatT (1536 x 512 bf16, n-major): [ L | quad_W1^T | cubic_W1^T ]
    int idx = b * 256 + tdx;
    int n = idx >> 9;
    int k = idx & 511;
    float v;
    if (n < 512) {
      float th = OMEGA_F * t[0];
      float s1, c1, s2, c2;
      sincosf(th, &s1, &c1);
      sincosf(2.0f * th, &s2, &c2);
      const float* p = fc + ((size_t)n * 512 + k) * 5;
      v = p[0] + p[1] * c1 + p[2] * s1 + p[3] * c2 + p[4] * s2;
    } else if (n < 1024) {
      v = qW1[(size_t)k * 512 + (n - 512)];
    } else {
      v = cW1[(size_t)k * 512 + (n - 1024)];
    }
    WT[idx] = f2bf(v);
  } else if (b < 3076) {
    int bb = b - 3072;
    const float* W = (bb < 2) ? qW2 : cW2;
    float* o = (bb < 2) ? qw2m : cw2m;
    int h = (bb & 1) * 256 + tdx;
    const float4* row = (const float4*)(W + (size_t)h * 512);
    float s = 0.f;
    for (int i = 0; i < 128; ++i) { float4 v = row[i]; s += (v.x + v.y) + (v.z + v.w); }
    o[h] = s * (1.0f / 512.0f);
  } else if (b == 3076) {
    __shared__ float sm[256];
    sm[tdx] = qb2[tdx] + qb2[tdx + 256];
    __syncthreads();
    for (int w = 128; w > 0; w >>= 1) { if (tdx < w) sm[tdx] += sm[tdx + w]; __syncthreads(); }
    if (tdx == 0) b2m[0] = sm[0] * (1.0f / 512.0f);
    __syncthreads();
    sm[tdx] = cb2[tdx] + cb2[tdx + 256];
    __syncthreads();
    for (int w = 128; w > 0; w >>= 1) { if (tdx < w) sm[tdx] += sm[tdx + w]; __syncthreads(); }
    if (tdx == 0) b2m[1] = sm[0] * (1.0f / 512.0f);
  } else if (b < 3077 + 8192) {
    // x -> bf16
    int i = (b - 3077) * 256 + tdx;
    float4 v = x4[i];
    uint2 r;
    r.x = (unsigned)f2bf(v.x) | ((unsigned)f2bf(v.y) << 16);
    r.y = (unsigned)f2bf(v.z) | ((unsigned)f2bf(v.w) << 16);
    xb[i] = r;
  } else {
    // enso tiny MLPs + rowadd zeroing
    int row = (b - 11269) * 256 + tdx;
    rowadd[row] = 0.f;
    float T = x[(size_t)row * 512];
    float H = x[(size_t)row * 512 + 1];
    float fT[5] = {T, H, T * T, T * H, T * T * T};
    float fH[5] = {T, H, T * T, T * H, T * H * H};
    float sT = tb2[0], sH = hb2[0];
#pragma unroll 4
    for (int e = 0; e < 32; ++e) {
      float a1 = tb1[e], a2 = hb1[e];
#pragma unroll
      for (int f = 0; f < 5; ++f) {
        a1 += fT[f] * tW1[f * 32 + e];
        a2 += fH[f] * hW1[f * 32 + e];
      }
      sT += fmaxf(a1, 0.f) * tW2[e];
      sH += fmaxf(a2, 0.f) * hW2[e];
    }
    cT[row] = sT;
    cH[row] = sH;
  }
}

// ---------------------------------------------------------------------------
// r3-verified 2-barrier GEMM main loop (used by lin_gemm): 128x128 tile,
// BK=64, gload_lds(16B), swizzle chunk(row,kc)->slot kc^(row&7).
// ---------------------------------------------------------------------------
#define GEMM_MAINLOOP(A_, Bt_, MB_, NB_)                                          \
  const int tid = threadIdx.x;                                                    \
  const int lane = tid & 63;                                                      \
  const int wave = tid >> 6;                                                      \
  const int wm = wave & 1;                                                        \
  const int wn = wave >> 1;                                                       \
  const int m_base = (MB_);                                                       \
  const int n_base = (NB_);                                                       \
  const int lrow = lane & 15;                                                     \
  const int l7 = lrow & 7;                                                        \
  const int kgrp = lane >> 4;                                                     \
  const int srow = lane >> 3;                                                     \
  const int sk = ((lane & 7) ^ srow) * 8;                                         \
  const unsigned short* gA0 = (A_) + (size_t)(m_base + wave * 8 + srow) * 512 + sk; \
  const unsigned short* gA1 = gA0 + 32 * 512;                                     \
  const unsigned short* gA2 = gA0 + 64 * 512;                                     \
  const unsigned short* gA3 = gA0 + 96 * 512;                                     \
  const unsigned short* gB0 = (Bt_) + (size_t)(n_base + wave * 8 + srow) * 512 + sk;\
  const unsigned short* gB1 = gB0 + 32 * 512;                                     \
  const unsigned short* gB2 = gB0 + 64 * 512;                                     \
  const unsigned short* gB3 = gB0 + 96 * 512;                                     \
  unsigned short* lA0 = As + wave * 512;                                          \
  unsigned short* lA1 = As + (4 + wave) * 512;                                    \
  unsigned short* lA2 = As + (8 + wave) * 512;                                    \
  unsigned short* lA3 = As + (12 + wave) * 512;                                   \
  unsigned short* lB0 = Bs + wave * 512;                                          \
  unsigned short* lB1 = Bs + (4 + wave) * 512;                                    \
  unsigned short* lB2 = Bs + (8 + wave) * 512;                                    \
  unsigned short* lB3 = Bs + (12 + wave) * 512;                                   \
  f32x4 acc[4][4];                                                                \
  _Pragma("unroll") for (int i = 0; i < 4; ++i)                                   \
      _Pragma("unroll") for (int j = 0; j < 4; ++j)                               \
          acc[i][j] = (f32x4){0.f, 0.f, 0.f, 0.f};                                \
  for (int k0 = 0; k0 < 512; k0 += 64) {                                          \
    gload16(gA0, lA0); gload16(gA1, lA1); gload16(gA2, lA2); gload16(gA3, lA3);   \
    gload16(gB0, lB0); gload16(gB1, lB1); gload16(gB2, lB2); gload16(gB3, lB3);   \
    gA0 += 64; gA1 += 64; gA2 += 64; gA3 += 64;                                   \
    gB0 += 64; gB1 += 64; gB2 += 64; gB3 += 64;                                   \
    __syncthreads();                                                              \
    _Pragma("unroll") for (int h = 0; h < 2; ++h) {                               \
      short8 af[4], bfr[4];                                                       \
      const int ks = ((h * 4 + kgrp) ^ l7) * 8;                                   \
      _Pragma("unroll") for (int i = 0; i < 4; ++i)                               \
          af[i] = *(const short8*)(&As[(wm * 64 + i * 16 + lrow) * 64 + ks]);     \
      _Pragma("unroll") for (int j = 0; j < 4; ++j)                               \
          bfr[j] = *(const short8*)(&Bs[(wn * 64 + j * 16 + lrow) * 64 + ks]);    \
      _Pragma("unroll") for (int i = 0; i < 4; ++i)                               \
          _Pragma("unroll") for (int j = 0; j < 4; ++j)                           \
              acc[i][j] = __builtin_amdgcn_mfma_f32_16x16x32_bf16(af[i], bfr[j],  \
                                                                  acc[i][j], 0, 0, 0); \
    }                                                                             \
    __syncthreads();                                                              \
  }

// ---------------------------------------------------------------------------
// nl_gemm8: 256x256 tile, 8-phase counted-vmcnt schedule. Grid (64,4), 512thr.
// ---------------------------------------------------------------------------
__global__ __launch_bounds__(512, 2) void nl_gemm8(
    const unsigned short* __restrict__ A,    // xb: 16384 x 512 bf16
    const unsigned short* __restrict__ Bt,   // 1024 x 512 bf16 (WT rows 512..1535)
    const float* __restrict__ qb1, const float* __restrict__ cb1,
    const float* __restrict__ qw2m, const float* __restrict__ cw2m,
    float* __restrict__ rowadd) {
  // ring[op][slot]: 256 rows x 32 k bf16 = 16 KB per half-tile. Total 128 KB.
  __shared__ unsigned short ring[2][4][8192];

  const int tid = threadIdx.x;
  const int lane = tid & 63;
  const int wv = tid >> 6;       // 0..7
  const int wm = wv >> 2;        // 0..1  (M half)
  const int wn = wv & 3;         // 0..3  (N quarter)
  const int lrow = lane & 15;
  const int kgrp = lane >> 4;    // 0..3
  const int m_base = blockIdx.x * 256;
  const int n_base = blockIdx.y * 256;

  // staging: lane l covers row (wv*32 + iss*16 + (l>>2)), LDS slot l&3,
  // global chunk kc2 = (l&3)^((l>>3)&3)  [slot = kc2 ^ ((row>>1)&3) inverse]
  const int srow0 = wv * 32 + (lane >> 2);
  const int skc = (lane & 3) ^ ((lane >> 3) & 3);
  const unsigned short* gA = A + (size_t)(m_base + srow0) * 512 + skc * 8;
  const unsigned short* gB = Bt + (size_t)(n_base + srow0) * 512 + skc * 8;

  // stage half s of operand op: k-columns [s*32, s*32+32)
#define STAGE_NL(op, s)                                                          \
  do {                                                                           \
    unsigned short* _l = &ring[op][(s) & 3][(wv * 32) * 32];                     \
    const unsigned short* _g = ((op) ? gB : gA) + (s) * 32;                      \
    gload16(_g, _l);                                                             \
    gload16(_g + 16 * 512, _l + 16 * 32);                                        \
  } while (0)

  f32x4 acc[8][4];
#pragma unroll
  for (int i = 0; i < 8; ++i)
#pragma unroll
    for (int j = 0; j < 4; ++j) acc[i][j] = (f32x4){0.f, 0.f, 0.f, 0.f};

  // prologue: halves s=0,1,2 for A and B (12 loads/thread)
  STAGE_NL(0, 0); STAGE_NL(1, 0);
  STAGE_NL(0, 1); STAGE_NL(1, 1);
  STAGE_NL(0, 2); STAGE_NL(1, 2);
  asm volatile("s_waitcnt vmcnt(4)" ::: "memory");  // s=0,1 landed
  __builtin_amdgcn_s_barrier();

#pragma unroll
  for (int t = 0; t < 8; ++t) {
#pragma unroll
    for (int p = 0; p < 4; ++p) {
      const int ph = t * 4 + p;
      const int h = p >> 1;       // k-half of this K-tile
      const int ihalf = p & 1;    // i-half (acc rows 0-3 vs 4-7)
      const int ra = (2 * t + h) & 3;

      // ds reads: 4 A-frags + 4 B-frags (guaranteed by barrier of phase ph-1)
      short8 af[4], bf[4];
#pragma unroll
      for (int ii = 0; ii < 4; ++ii) {
        const int row = wm * 128 + ihalf * 64 + ii * 16 + lrow;
        const int sw = kgrp ^ ((row >> 1) & 3);
        af[ii] = *(const short8*)(&ring[0][ra][row * 32 + sw * 8]);
      }
#pragma unroll
      for (int j = 0; j < 4; ++j) {
        const int row = wn * 64 + j * 16 + lrow;
        const int sw = kgrp ^ ((row >> 1) & 3);
        bf[j] = *(const short8*)(&ring[1][ra][row * 32 + sw * 8]);
      }

      // stage one half-tile: s = (ph>>1)+3, op = ph&1; slot's previous
      // occupant (s-4) was last read at phase 2(s-4)+1 = ph-1 (barriered).
      if (ph <= 25) {
        const int s = (ph >> 1) + 3;
        if ((ph & 1) == 0) STAGE_NL(0, s);
        else               STAGE_NL(1, s);
      }

      // counted wait: publish "halves staged <= ph-4 arrived" at the barrier.
      // outstanding = halves staged in phases [ph-3..ph] (2 loads each).
      if (ph <= 25)      asm volatile("s_waitcnt vmcnt(8)" ::: "memory");
      else if (ph == 26) asm volatile("s_waitcnt vmcnt(6)" ::: "memory");
      else if (ph == 27) asm volatile("s_waitcnt vmcnt(4)" ::: "memory");
      else if (ph == 28) asm volatile("s_waitcnt vmcnt(2)" ::: "memory");
      else               asm volatile("s_waitcnt vmcnt(0)" ::: "memory");
      __builtin_amdgcn_s_barrier();

      __builtin_amdgcn_s_setprio(1);
#pragma unroll
      for (int ii = 0; ii < 4; ++ii)
#pragma unroll
        for (int j = 0; j < 4; ++j)
          acc[ihalf * 4 + ii][j] = __builtin_amdgcn_mfma_f32_16x16x32_bf16(
              af[ii], bf[j], acc[ihalf * 4 + ii][j], 0, 0, 0);
      __builtin_amdgcn_s_setprio(0);
      __builtin_amdgcn_s_barrier();
    }
  }
#undef STAGE_NL

  // epilogue: relu.w2m fold, lrow shuffle-reduce, rowadd atomics.
  // C/D: col = lane&15, row = kgrp*4 + reg (m89/m91).
  const bool isq = (n_base < 512);
  const float* b1p = isq ? qb1 : cb1;
  const float* w2m = isq ? qw2m : cw2m;
  const int cb0 = (isq ? n_base : n_base - 512) + wn * 64 + lrow;
  float rs[8][4];
#pragma unroll
  for (int i = 0; i < 8; ++i)
#pragma unroll
    for (int r = 0; r < 4; ++r) rs[i][r] = 0.f;
#pragma unroll
  for (int j = 0; j < 4; ++j) {
    const int col = cb0 + j * 16;
    const float bb = b1p[col];
    const float ww = w2m[col];
#pragma unroll
    for (int i = 0; i < 8; ++i)
#pragma unroll
      for (int r = 0; r < 4; ++r)
        rs[i][r] += fmaxf(acc[i][j][r] + bb, 0.f) * ww;
  }
  const int rbase = m_base + wm * 128 + kgrp * 4;
#pragma unroll
  for (int i = 0; i < 8; ++i)
#pragma unroll
    for (int r = 0; r < 4; ++r) {
      float v = rs[i][r];
      v += __shfl_xor(v, 1, 64);
      v += __shfl_xor(v, 2, 64);
      v += __shfl_xor(v, 4, 64);
      v += __shfl_xor(v, 8, 64);
      if (lrow == 0) atomicAdd(&rowadd[rbase + i * 16 + r], v);
    }
}

// ---- phase 2: x @ L^T, epilogue folds rowadd + b2 means + enso -> out ------
__global__ __launch_bounds__(256) void lin_gemm(
    const unsigned short* __restrict__ A,    // 16384 x 512 bf16
    const unsigned short* __restrict__ Bt,   // 512 x 512 bf16 (WT rows 0..511)
    const float* __restrict__ rowadd, const float* __restrict__ b2m,
    const float* __restrict__ cT, const float* __restrict__ cH,
    float* __restrict__ out) {
  __shared__ unsigned short As[128 * 64];
  __shared__ unsigned short Bs[128 * 64];
  GEMM_MAINLOOP(A, Bt, blockIdx.x * 128, blockIdx.y * 128)
  const int rbase = m_base + wm * 64 + (lane >> 4) * 4;
  const float b2s = b2m[0] + b2m[1];
  float ra[4][4];
#pragma unroll
  for (int i = 0; i < 4; ++i)
#pragma unroll
    for (int r = 0; r < 4; ++r) ra[i][r] = rowadd[rbase + i * 16 + r] + b2s;
#pragma unroll
  for (int j = 0; j < 4; ++j) {
    int col = n_base + wn * 64 + j * 16 + lrow;
#pragma unroll
    for (int i = 0; i < 4; ++i)
#pragma unroll
      for (int r = 0; r < 4; ++r) {
        int row = rbase + i * 16 + r;
        float v = acc[i][j][r] + ra[i][r];
        if (col == 0) v += cT[row];
        if (col == 1) v += cH[row];
        out[(size_t)row * 512 + col] = v;
      }
  }
}

extern "C" void kernel_launch(void* const* d_in, const int* in_sizes, int n_in,
                              void* d_out, int out_size, void* d_ws, size_t ws_size,
                              hipStream_t stream) {
  const float* x   = (const float*)d_in[0];
  const float* t   = (const float*)d_in[1];
  const float* fc  = (const float*)d_in[2];
  const float* qW1 = (const float*)d_in[3];
  const float* qb1 = (const float*)d_in[4];
  const float* qW2 = (const float*)d_in[5];
  const float* qb2 = (const float*)d_in[6];
  const float* cW1 = (const float*)d_in[7];
  const float* cb1 = (const float*)d_in[8];
  const float* cW2 = (const float*)d_in[9];
  const float* cb2 = (const float*)d_in[10];
  const float* tW1 = (const float*)d_in[11];
  const float* tb1 = (const float*)d_in[12];
  const float* tW2 = (const float*)d_in[13];
  const float* tb2 = (const float*)d_in[14];
  const float* hW1 = (const float*)d_in[15];
  const float* hb1 = (const float*)d_in[16];
  const float* hW2 = (const float*)d_in[17];
  const float* hb2 = (const float*)d_in[18];
  float* out = (float*)d_out;

  // workspace layout (bytes); total ~18.6 MB
  char* ws = (char*)d_ws;
  unsigned short* WT = (unsigned short*)(ws);              // 1536*512*2   = 1,572,864
  unsigned short* xb = (unsigned short*)(ws + 1572864);    // 16384*512*2  = 16,777,216
  float* qw2m   = (float*)(ws + 18350080);                 // 512*4
  float* cw2m   = (float*)(ws + 18352128);                 // 512*4
  float* b2m    = (float*)(ws + 18354176);                 // 2*4 (pad)
  float* cT     = (float*)(ws + 18354432);                 // 16384*4
  float* cH     = (float*)(ws + 18419968);                 // 16384*4
  float* rowadd = (float*)(ws + 18485504);                 // 16384*4 -> ends 18,551,040

  prep_conv<<<11333, 256, 0, stream>>>(fc, qW1, cW1, t, qW2, cW2, qb2, cb2,
                                       (const float4*)x, x,
                                       tW1, tb1, tW2, tb2, hW1, hb1, hW2, hb2,
                                       WT, (uint2*)xb, qw2m, cw2m, b2m, cT, cH,
                                       rowadd);
  nl_gemm8<<<dim3(64, 4), 512, 0, stream>>>(xb, WT + (size_t)512 * 512,
                                            qb1, cb1, qw2m, cw2m, rowadd);
  lin_gemm<<<dim3(128, 4), 256, 0, stream>>>(xb, WT, rowadd, b2m, cT, cH, out);
}